// Round 6
// baseline (21350.273 us; speedup 1.0000x reference)
//
#include <hip/hip_runtime.h>

typedef _Float16 f16;
typedef __attribute__((ext_vector_type(8))) _Float16 f16x8;
typedef __attribute__((ext_vector_type(4))) float f32x4;

#define NBATCH 1024
#define NH 1024
#define NT 336
#define NDFF 7
#define NQ 9
#define K0 1088   /* 64 (x padded) + 1024 (h0) */
#define K1 2048   /* 1024 (h0_new) + 1024 (h1) */
#define OUTSTRIDE (NT * NQ)

__device__ __forceinline__ float sigf(float x) { return 1.0f / (1.0f + __expf(-x)); }
__device__ __forceinline__ float tanhfast(float x) { return 1.0f - 2.0f / (__expf(2.0f * x) + 1.0f); }

// plain (L2-cached) staging — used for BOTH weights and h now. h coherence is
// provided by agent-acquire fences at the two spin-gates (see persist()).
__device__ __forceinline__ void gll(const void* g, void* l) {
  __builtin_amdgcn_global_load_lds((const __attribute__((address_space(1))) void*)g,
                                   (__attribute__((address_space(3))) void*)l, 16, 0, 0);
}

__device__ __forceinline__ void spinGE(unsigned int* c, unsigned int tgt) {
  while (__hip_atomic_load(c, __ATOMIC_RELAXED, __HIP_MEMORY_SCOPE_AGENT) < tgt) {
    __builtin_amdgcn_s_sleep(2);
  }
}

// coherent 16B store (write-through so post-fence cross-XCD readers see it)
__device__ __forceinline__ void store16_coherent(void* p, f16x8 v) {
  asm volatile("global_store_dwordx4 %0, %1, off sc0 sc1" :: "v"(p), "v"(v) : "memory");
}

// ---------------------------------------------------------------------------
// Weight pack: rows permuted so LDS B-tile row p (0..127 within colblock cb):
//   gate = (p>>4)&3, hcol_local = (p>>6)*16 + (p&15)  -> MFMA n-index == gate.
// k pre-swizzled within each 64-col chunk: dst_k = (k&~63)|((k&63)^((p&7)<<3)).
// ---------------------------------------------------------------------------
__global__ void pack_w0(const float* __restrict__ Wih0, const float* __restrict__ Whh0,
                        f16* __restrict__ Wp0) {
  const int idx = blockIdx.x * 256 + threadIdx.x;  // exactly 4096*K0
  const int pr = idx / K0;
  const int dk = idx - pr * K0;
  const int cb = pr >> 7, p = pr & 127;
  const int gate = (p >> 4) & 3;
  const int hl = ((p >> 6) << 4) | (p & 15);
  const int j = (gate << 10) + (cb << 5) + hl;
  const int sk = (dk & ~63) | ((dk & 63) ^ ((p & 7) << 3));
  float v;
  if (sk < 8) v = Wih0[j * 8 + sk];          // col 0 = y feedback, 1..7 = features
  else if (sk < 64) v = 0.0f;                // pad
  else v = Whh0[(size_t)j * NH + (sk - 64)];
  Wp0[idx] = (f16)v;
}

__global__ void pack_w1(const float* __restrict__ Wih1, const float* __restrict__ Whh1,
                        f16* __restrict__ Wp1) {
  const int idx = blockIdx.x * 256 + threadIdx.x;  // exactly 4096*2048
  const int pr = idx >> 11;
  const int dk = idx & 2047;
  const int cb = pr >> 7, p = pr & 127;
  const int gate = (p >> 4) & 3;
  const int hl = ((p >> 6) << 4) | (p & 15);
  const int j = (gate << 10) + (cb << 5) + hl;
  const int sk = (dk & ~63) | ((dk & 63) ^ ((p & 7) << 3));
  const float v = (sk < 1024) ? Wih1[(size_t)j * NH + sk]
                              : Whh1[(size_t)j * NH + (sk - 1024)];
  Wp1[idx] = (f16)v;
}

__global__ void pack_misc(const float* __restrict__ a0, const float* __restrict__ b0,
                          const float* __restrict__ a1, const float* __restrict__ b1,
                          float* __restrict__ bias0, float* __restrict__ bias1,
                          unsigned int* __restrict__ cnt) {
  const int j = blockIdx.x * 256 + threadIdx.x;
  if (j < 4096) { bias0[j] = a0[j] + b0[j]; bias1[j] = a1[j] + b1[j]; }
  if (j < 16) cnt[j] = 0;   // aCnt[8], bCnt[8] reset every call
}

// h state stored fp16 pre-swizzled (chunk swizzle keyed by row&7).
__global__ void init_h(const float* __restrict__ h_in,
                       f16* __restrict__ h0, f16* __restrict__ h1) {
  const int idx = blockIdx.x * 256 + threadIdx.x;  // exactly 2*1024*1024
  const int l = idx >> 20;
  const int rc = idx & 1048575;
  const int row = rc >> 10;
  const int dk = idx & 1023;
  const int sk = (dk & ~63) | ((dk & 63) ^ ((row & 7) << 3));
  const float hv = h_in[((size_t)l << 20) + ((size_t)row << 10) + sk];
  if (l == 0) h0[rc] = (f16)hv;
  else        h1[rc] = (f16)hv;
}

// Sum y partials for the last timestep (t = 335).
__global__ void final_y(const float* __restrict__ ypartT, const float* __restrict__ bout,
                        float* __restrict__ dout) {
  const int idx = blockIdx.x * 256 + threadIdx.x;  // exactly 9216
  const int row = idx & 1023;
  const int q = idx >> 10;
  float s = bout[q];
#pragma unroll
  for (int nb2 = 0; nb2 < 32; ++nb2) s += ypartT[(((q << 5) + nb2) << 10) + row];
  dout[(size_t)row * OUTSTRIDE + 335 * NQ + q] = s;
}

// ---------------------------------------------------------------------------
// Persistent kernel, 4-slot LDS ring, stage-ahead 3, COUNTED vmcnt ledger.
// Per iter (reordered r5->r6): s_barrier (slot sc+3 free: its readers done)
//   -> issue stage(sc+3) -> s_waitcnt vmcnt(N) lgkmcnt(0) -> compute(sc).
// N = sum of gll counts of stages sc+1..sc+3 (8 each; x-stage at A-g13 = 4):
//   phase A g13/g14/g15 -> 20, else 24; phase B all 24.
// h COHERENCE (new): h loads are PLAIN cached. Stale-line analysis:
//   h0prev reads (A iters, B tail) re-read data already read last step with
//   no intervening write -> cache-safe. First-touch windows needing fresh
//   data: h1prev (written t-1 phase B) first read after A-g13; h0new
//   (written t phase A) first read at B-b13. An agent-acquire FENCE
//   (buffer_inv) right after each spin-gate invalidates stale L1/L2 lines;
//   producers publish via sc0sc1 write-through + vmcnt(0) before cnt bump.
// ---------------------------------------------------------------------------
__global__ __launch_bounds__(256, 1) void persist(
    const f16* __restrict__ Wp0, const f16* __restrict__ Wp1,
    const float* __restrict__ bias0, const float* __restrict__ bias1,
    f16* __restrict__ h0b0, f16* __restrict__ h0b1,
    f16* __restrict__ h1b0, f16* __restrict__ h1b1,
    unsigned int* __restrict__ cnt,
    const float* __restrict__ ff, const float* __restrict__ inpy,
    float* __restrict__ ypartT, const float* __restrict__ Wout,
    const float* __restrict__ bout, const float* __restrict__ c_in,
    float* __restrict__ dout) {
  __shared__ __align__(16) unsigned char lds8[131072];   // 4 x 32KB ring

  const int tid = threadIdx.x;
  const int wv = tid >> 6;
  const int ln = tid & 63;
  const int wr = wv >> 1, wc = wv & 1;
  const int blk = blockIdx.x;
  const int rb = (blk >> 3) & 7;
  const int cb = (blk & 7) * 4 + (blk >> 6);   // XCD-striped colblocks
  const int row0 = rb * 128;
  const int hcol0 = cb * 32;
  unsigned int* aCnt = cnt + rb;
  unsigned int* bCnt = cnt + 8 + rb;

  f16* h0arr[2] = {h0b0, h0b1};
  f16* h1arr[2] = {h1b0, h1b1};

  const int lanerow = ln & 15;
  const int xm = (ln & 7) << 4;
  const int kgrp = (ln >> 4) << 4;
  const int hcol = hcol0 + wc * 16 + lanerow;

  // c state lives in registers for the whole run
  float c0r[4][4], c1r[4][4];
#pragma unroll
  for (int m = 0; m < 4; ++m)
#pragma unroll
    for (int r = 0; r < 4; ++r) {
      const int row = row0 + wr * 64 + m * 16 + ((ln >> 4) << 2) + r;
      c0r[m][r] = c_in[(size_t)row * NH + hcol];
      c1r[m][r] = c_in[(size_t)(NBATCH * NH) + (size_t)row * NH + hcol];
    }

  const float b0i = bias0[hcol], b0f = bias0[NH + hcol],
              b0g = bias0[2 * NH + hcol], b0o = bias0[3 * NH + hcol];
  const float b1i = bias1[hcol], b1f = bias1[NH + hcol],
              b1g = bias1[2 * NH + hcol], b1o = bias1[3 * NH + hcol];

  auto stW = [&](const f16* W, int KDIM, int kt, int slot) {
#pragma unroll
    for (int i = 0; i < 4; ++i) {
      const int ci = wv * 4 + i;
      const int tr = ci * 8 + (ln >> 3);
      gll(W + (size_t)(cb * 128 + tr) * KDIM + kt * 64 + (ln & 7) * 8,
          lds8 + slot * 32768 + 16384 + ci * 1024);
    }
  };
  auto stH = [&](const f16* h, int kb, int slot) {
#pragma unroll
    for (int i = 0; i < 4; ++i) {
      const int ci = wv * 4 + i;
      const int r = ci * 8 + (ln >> 3);
      gll(h + (((size_t)(row0 + r)) << 10) + kb + (ln & 7) * 8,
          lds8 + slot * 32768 + ci * 1024);
    }
  };

  f32x4 acc[4][4];
  const f32x4 zf = {0.0f, 0.0f, 0.0f, 0.0f};
#pragma unroll
  for (int m = 0; m < 4; ++m)
#pragma unroll
    for (int n = 0; n < 4; ++n) acc[m][n] = zf;

  auto compute = [&](int slot) {
    const unsigned char* Ab = lds8 + slot * 32768;
    const unsigned char* Bb = Ab + 16384;
#pragma unroll
    for (int ks = 0; ks < 2; ++ks) {
      const int kb = (kgrp + ks * 64) ^ xm;
      f16x8 afr[4], bfr[4];
#pragma unroll
      for (int m = 0; m < 4; ++m)
        afr[m] = *(const f16x8*)(Ab + (wr * 64 + m * 16 + lanerow) * 128 + kb);
#pragma unroll
      for (int n = 0; n < 4; ++n)
        bfr[n] = *(const f16x8*)(Bb + (wc * 64 + n * 16 + lanerow) * 128 + kb);
      __builtin_amdgcn_s_setprio(1);
#pragma unroll
      for (int m = 0; m < 4; ++m)
#pragma unroll
        for (int n = 0; n < 4; ++n)
          acc[m][n] = __builtin_amdgcn_mfma_f32_16x16x32_f16(afr[m], bfr[n], acc[m][n], 0, 0, 0);
      __builtin_amdgcn_s_setprio(0);
    }
  };

  // epilogue helper: hbuf (in freed slot) f32 [128][36] -> fp16 swizzled 16B
  // coherent stores (2 units/thread, each unit = 8 cols of one row)
  auto h_widestore = [&](f16* hdst, float* hb) {
#pragma unroll
    for (int u2 = 0; u2 < 2; ++u2) {
      const int unit = tid * 2 + u2;          // 0..511
      const int r = unit >> 2;                // block-local row
      const int u = unit & 3;                 // 8-col group
      const f32x4 lo = *(const f32x4*)(hb + r * 36 + u * 8);
      const f32x4 hi = *(const f32x4*)(hb + r * 36 + u * 8 + 4);
      f16x8 v;
#pragma unroll
      for (int j = 0; j < 4; ++j) { v[j] = (f16)lo[j]; v[4 + j] = (f16)hi[j]; }
      const int rowg = row0 + r;
      const int pb = ((hcol0 & 63) << 1) + u * 16;   // plain byte in 128B chunk
      void* p = (unsigned char*)hdst + (size_t)rowg * 2048 + ((hcol0 >> 6) << 7) +
                (pb ^ ((rowg & 7) << 4));
      store16_coherent(p, v);
    }
  };

  // ---- prologue: stage A_0 tiles 0,1,2 into slots 0,1,2 ----
  stH(h0arr[0], 0, 0);   stW(Wp0, K0, 1, 0);
  stH(h0arr[0], 64, 1);  stW(Wp0, K0, 2, 1);
  stH(h0arr[0], 128, 2); stW(Wp0, K0, 3, 2);

  int sc = 0;  // global slot counter (slot = sc & 3)

  for (int t = 0; t < NT; ++t) {
    const int p = t & 1;
    const f16* h0prev = h0arr[p];
    f16* h0new = h0arr[1 - p];
    const f16* h1prev = h1arr[p];
    f16* h1new = h1arr[1 - p];

    // ========== PHASE A (layer 0): 17 tiles, order kt = 1..16 then 0(x) =====
#pragma unroll 1
    for (int g = 0; g < 17; ++g) {
      __builtin_amdgcn_sched_barrier(0);
      __builtin_amdgcn_s_barrier();       // slot sc+3 free: its readers done
      __builtin_amdgcn_sched_barrier(0);
      const int cslot = sc & 3;
      const int tslot = (sc + 3) & 3;

      if (g == 13) {
        // gate on siblings' B_{t-1}: ypart ready (x feedback + y[t-1] out)
        if (t > 0) {
          if (tid == 0) spinGE(bCnt, 32u * (unsigned)t);
          __builtin_amdgcn_s_barrier();
        }
        // ACQUIRE: invalidate stale L1/L2 lines of h1prev (and anything else
        // written cross-XCD since our last fence) before its first-touch
        // staging at g14+. Emits waitcnt+buffer_inv.
        __builtin_amdgcn_fence(__ATOMIC_ACQUIRE, "agent");
        __builtin_amdgcn_sched_barrier(0);
        unsigned char* xb = lds8 + tslot * 32768;
        if (tid < 128) {
          const int row = row0 + tid;
          float y0;
          if (t == 0) {
            y0 = inpy[row];
          } else {
            y0 = bout[0];
#pragma unroll
            for (int nb2 = 0; nb2 < 32; ++nb2)
              y0 += __hip_atomic_load(ypartT + (nb2 << 10) + row,
                                      __ATOMIC_RELAXED, __HIP_MEMORY_SCOPE_AGENT);
          }
          const float* fsrc = ff + ((size_t)row * NT + t) * NDFF;
          f16x8 xv;
          xv[0] = (f16)y0;
#pragma unroll
          for (int jj = 0; jj < 7; ++jj) xv[1 + jj] = (f16)fsrc[jj];
          *(f16x8*)(xb + tid * 128 + ((tid & 7) << 4)) = xv;
        }
        f16x8 zv;
#pragma unroll
        for (int jj = 0; jj < 8; ++jj) zv[jj] = (f16)0.0f;
        for (int idx = tid; idx < 128 * 7; idx += 256) {
          const int r = idx / 7;
          const int ch = 1 + (idx - r * 7);
          *(f16x8*)(xb + r * 128 + ((ch ^ (r & 7)) << 4)) = zv;
        }
        if (t > 0 && cb < NQ && tid < 128) {   // emit y[t-1]
          const int row = row0 + tid;
          float s = bout[cb];
#pragma unroll
          for (int nb2 = 0; nb2 < 32; ++nb2)
            s += __hip_atomic_load(ypartT + (((cb << 5) + nb2) << 10) + row,
                                   __ATOMIC_RELAXED, __HIP_MEMORY_SCOPE_AGENT);
          dout[(size_t)row * OUTSTRIDE + (t - 1) * NQ + cb] = s;
        }
        stW(Wp0, K0, 0, tslot);   // 4 loads only
      } else {
        const int idx = g + 3;
        if (idx <= 15)      { stH(h0prev, idx * 64, tslot); stW(Wp0, K0, idx + 1, tslot); }
        else if (idx == 17) { stH(h1prev, 0, tslot);        stW(Wp1, K1, 16, tslot); }
        else if (idx == 18) { stH(h1prev, 64, tslot);       stW(Wp1, K1, 17, tslot); }
        else                { stH(h1prev, 128, tslot);      stW(Wp1, K1, 18, tslot); }
      }
      // counted wait: stage(sc) landed; stages sc+1..sc+3 stay in flight
      if (g >= 13 && g <= 15) asm volatile("s_waitcnt vmcnt(20) lgkmcnt(0)" ::: "memory");
      else                    asm volatile("s_waitcnt vmcnt(24) lgkmcnt(0)" ::: "memory");
      __builtin_amdgcn_sched_barrier(0);
      compute(cslot);
      ++sc;
    }

    // ---- A epilogue: layer-0 cell update -> hbuf -> wide coherent stores ----
    {
      // barrier: other waves may still be ds_reading the freed slot (x-slot)
      __builtin_amdgcn_s_barrier();
      float* hb = (float*)(lds8 + ((sc - 1) & 3) * 32768);
#pragma unroll
      for (int m = 0; m < 4; ++m) {
        const f32x4 vi = acc[m][0], vf = acc[m][1], vg = acc[m][2], vo = acc[m][3];
#pragma unroll
        for (int r = 0; r < 4; ++r) {
          const int rloc = wr * 64 + m * 16 + ((ln >> 4) << 2) + r;
          const float ig = sigf(vi[r] + b0i);
          const float fg = sigf(vf[r] + b0f);
          const float gg = tanhfast(vg[r] + b0g);
          const float og = sigf(vo[r] + b0o);
          const float cn = fg * c0r[m][r] + ig * gg;
          c0r[m][r] = cn;
          hb[rloc * 36 + wc * 16 + lanerow] = og * tanhfast(cn);
        }
        acc[m][0] = zf; acc[m][1] = zf; acc[m][2] = zf; acc[m][3] = zf;
      }
      asm volatile("s_waitcnt lgkmcnt(0)" ::: "memory");
      __builtin_amdgcn_s_barrier();
      h_widestore(h0new, hb);
      asm volatile("s_waitcnt vmcnt(0)" ::: "memory");  // h0 stores visible
      __builtin_amdgcn_s_barrier();
      if (tid == 0)
        __hip_atomic_fetch_add(aCnt, 1u, __ATOMIC_RELAXED, __HIP_MEMORY_SCOPE_AGENT);
    }

    // ========== PHASE B (layer 1): 32 tiles, order = h1prev k0..15, h0new k0..15
#pragma unroll 1
    for (int b = 0; b < 32; ++b) {
      __builtin_amdgcn_sched_barrier(0);
      __builtin_amdgcn_s_barrier();
      __builtin_amdgcn_sched_barrier(0);
      const int cslot = sc & 3;
      const int tslot = (sc + 3) & 3;

      if (b == 13) {  // gate h0new staging on all group-mates' phase A
        if (tid == 0) spinGE(aCnt, 32u * (unsigned)(t + 1));
        __builtin_amdgcn_s_barrier();
        // ACQUIRE: invalidate stale lines of h0new before first-touch staging
        // (stH(h0new, 0) issued THIS iteration, below).
        __builtin_amdgcn_fence(__ATOMIC_ACQUIRE, "agent");
        __builtin_amdgcn_sched_barrier(0);
      }
      const int idx = b + 3;
      if (idx <= 15)      { stH(h1prev, idx * 64, tslot);        stW(Wp1, K1, 16 + idx, tslot); }
      else if (idx <= 31) { stH(h0new, (idx - 16) * 64, tslot);  stW(Wp1, K1, idx - 16, tslot); }
      else                { stH(h0new, (idx - 32) * 64, tslot);  stW(Wp0, K0, idx - 31, tslot); }
      asm volatile("s_waitcnt vmcnt(24) lgkmcnt(0)" ::: "memory");
      __builtin_amdgcn_sched_barrier(0);
      compute(cslot);
      ++sc;
    }

    // ---- B epilogue: layer-1 cell update; h1 wide stores + ypart ----
    {
      __builtin_amdgcn_s_barrier();   // freed slot may still be under ds_read
      float* hb = (float*)(lds8 + ((sc - 1) & 3) * 32768);
#pragma unroll
      for (int m = 0; m < 4; ++m) {
        const f32x4 vi = acc[m][0], vf = acc[m][1], vg = acc[m][2], vo = acc[m][3];
#pragma unroll
        for (int r = 0; r < 4; ++r) {
          const int rloc = wr * 64 + m * 16 + ((ln >> 4) << 2) + r;
          const float ig = sigf(vi[r] + b1i);
          const float fg = sigf(vf[r] + b1f);
          const float gg = tanhfast(vg[r] + b1g);
          const float og = sigf(vo[r] + b1o);
          const float cn = fg * c1r[m][r] + ig * gg;
          c1r[m][r] = cn;
          hb[rloc * 36 + wc * 16 + lanerow] = og * tanhfast(cn);
        }
        acc[m][0] = zf; acc[m][1] = zf; acc[m][2] = zf; acc[m][3] = zf;
      }
      asm volatile("s_waitcnt lgkmcnt(0)" ::: "memory");
      __builtin_amdgcn_s_barrier();
      h_widestore(h1new, hb);
      // y partials over this block's 32 h-cols: ypartT[q][cb][row]
      for (int task = tid; task < 128 * NQ; task += 256) {
        const int rloc = task & 127;
        const int q = task >> 7;
        const float* wq = Wout + q * NH + hcol0;
        float s = 0.0f;
#pragma unroll
        for (int c2 = 0; c2 < 32; ++c2) s += hb[rloc * 36 + c2] * wq[c2];
        __hip_atomic_store(ypartT + (size_t)((q << 5) + cb) * 1024 + row0 + rloc, s,
                           __ATOMIC_RELAXED, __HIP_MEMORY_SCOPE_AGENT);
      }
      asm volatile("s_waitcnt vmcnt(0)" ::: "memory");  // h1 + ypart visible
      __builtin_amdgcn_s_barrier();
      if (tid == 0)
        __hip_atomic_fetch_add(bCnt, 1u, __ATOMIC_RELAXED, __HIP_MEMORY_SCOPE_AGENT);
    }
  }
}

// ---------------------------------------------------------------------------
extern "C" void kernel_launch(void* const* d_in, const int* in_sizes, int n_in,
                              void* d_out, int out_size, void* d_ws, size_t ws_size,
                              hipStream_t stream) {
  const float* inpy = (const float*)d_in[2];
  const float* h_in = (const float*)d_in[3];
  const float* c_in = (const float*)d_in[4];
  const float* ff   = (const float*)d_in[5];
  const float* Wih0 = (const float*)d_in[9];
  const float* Whh0 = (const float*)d_in[10];
  const float* bih0 = (const float*)d_in[11];
  const float* bhh0 = (const float*)d_in[12];
  const float* Wih1 = (const float*)d_in[13];
  const float* Whh1 = (const float*)d_in[14];
  const float* bih1 = (const float*)d_in[15];
  const float* bhh1 = (const float*)d_in[16];
  const float* Wout = (const float*)d_in[17];
  const float* bout = (const float*)d_in[18];
  float* dout = (float*)d_out;

  unsigned char* ws = (unsigned char*)d_ws;
  size_t off = 0;
  auto alloc = [&](size_t bytes) -> void* {
    void* p = ws + off;
    off += (bytes + 255) & ~(size_t)255;
    return p;
  };
  f16* Wp0 = (f16*)alloc((size_t)4096 * K0 * 2);
  f16* Wp1 = (f16*)alloc((size_t)4096 * K1 * 2);
  f16* h0b0 = (f16*)alloc((size_t)NBATCH * NH * 2);
  f16* h0b1 = (f16*)alloc((size_t)NBATCH * NH * 2);
  f16* h1b0 = (f16*)alloc((size_t)NBATCH * NH * 2);
  f16* h1b1 = (f16*)alloc((size_t)NBATCH * NH * 2);
  float* bias0 = (float*)alloc(4096 * 4);
  float* bias1 = (float*)alloc(4096 * 4);
  float* ypartT = (float*)alloc((size_t)NQ * 32 * 1024 * 4);
  unsigned int* cnt = (unsigned int*)alloc(64);

  pack_w0<<<(4096 * K0) / 256, 256, 0, stream>>>(Wih0, Whh0, Wp0);
  pack_w1<<<(4096 * K1) / 256, 256, 0, stream>>>(Wih1, Whh1, Wp1);
  pack_misc<<<16, 256, 0, stream>>>(bih0, bhh0, bih1, bhh1, bias0, bias1, cnt);
  init_h<<<(2 * NBATCH * NH) / 256, 256, 0, stream>>>(h_in, h0b0, h1b0);

  persist<<<256, 256, 0, stream>>>(Wp0, Wp1, bias0, bias1, h0b0, h0b1, h1b0, h1b1,
                                   cnt, ff, inpy, ypartT, Wout, bout, c_in, dout);

  final_y<<<36, 256, 0, stream>>>(ypartT, bout, dout);
}

// Round 7
// 17221.767 us; speedup vs baseline: 1.2397x; 1.2397x over previous
//
#include <hip/hip_runtime.h>

typedef _Float16 f16;
typedef __attribute__((ext_vector_type(8))) _Float16 f16x8;
typedef __attribute__((ext_vector_type(4))) float f32x4;

#define NBATCH 1024
#define NH 1024
#define NT 336
#define NDFF 7
#define NQ 9
#define K0 1088   /* 64 (x padded) + 1024 (h0) */
#define K1 2048   /* 1024 (h0_new) + 1024 (h1) */
#define OUTSTRIDE (NT * NQ)

__device__ __forceinline__ float sigf(float x) { return 1.0f / (1.0f + __expf(-x)); }
__device__ __forceinline__ float tanhfast(float x) { return 1.0f - 2.0f / (__expf(2.0f * x) + 1.0f); }

// plain (L2-cached) staging for weights
__device__ __forceinline__ void gll_w(const void* g, void* l) {
  __builtin_amdgcn_global_load_lds((const __attribute__((address_space(1))) void*)g,
                                   (__attribute__((address_space(3))) void*)l, 16, 0, 0);
}
// agent-coherent staging for h state (SC0|SC1): reads through to L3 (fresh data)
__device__ __forceinline__ void gll_c(const void* g, void* l) {
  __builtin_amdgcn_global_load_lds((const __attribute__((address_space(1))) void*)g,
                                   (__attribute__((address_space(3))) void*)l, 16, 0, 17);
}

__device__ __forceinline__ void spinGE(unsigned int* c, unsigned int tgt) {
  while (__hip_atomic_load(c, __ATOMIC_RELAXED, __HIP_MEMORY_SCOPE_AGENT) < tgt) {
    __builtin_amdgcn_s_sleep(2);
  }
}

// coherent 16B store (write-through so cross-XCD sc1 readers see it)
__device__ __forceinline__ void store16_coherent(void* p, f16x8 v) {
  asm volatile("global_store_dwordx4 %0, %1, off sc0 sc1" :: "v"(p), "v"(v) : "memory");
}

// ---------------------------------------------------------------------------
// Weight pack: rows permuted so LDS B-tile row p (0..127 within colblock cb):
//   gate = (p>>4)&3, hcol_local = (p>>6)*16 + (p&15)  -> MFMA n-index == gate
//   for BOTH the 2-N-wave (64-row) split.  k pre-swizzled per 64-col chunk:
//   dst_k = (k&~63)|((k&63)^((p&7)<<3)).
// ---------------------------------------------------------------------------
__global__ void pack_w0(const float* __restrict__ Wih0, const float* __restrict__ Whh0,
                        f16* __restrict__ Wp0) {
  const int idx = blockIdx.x * 256 + threadIdx.x;  // exactly 4096*K0
  const int pr = idx / K0;
  const int dk = idx - pr * K0;
  const int cb = pr >> 7, p = pr & 127;
  const int gate = (p >> 4) & 3;
  const int hl = ((p >> 6) << 4) | (p & 15);
  const int j = (gate << 10) + (cb << 5) + hl;
  const int sk = (dk & ~63) | ((dk & 63) ^ ((p & 7) << 3));
  float v;
  if (sk < 8) v = Wih0[j * 8 + sk];          // col 0 = y feedback, 1..7 = features
  else if (sk < 64) v = 0.0f;                // pad
  else v = Whh0[(size_t)j * NH + (sk - 64)];
  Wp0[idx] = (f16)v;
}

__global__ void pack_w1(const float* __restrict__ Wih1, const float* __restrict__ Whh1,
                        f16* __restrict__ Wp1) {
  const int idx = blockIdx.x * 256 + threadIdx.x;  // exactly 4096*2048
  const int pr = idx >> 11;
  const int dk = idx & 2047;
  const int cb = pr >> 7, p = pr & 127;
  const int gate = (p >> 4) & 3;
  const int hl = ((p >> 6) << 4) | (p & 15);
  const int j = (gate << 10) + (cb << 5) + hl;
  const int sk = (dk & ~63) | ((dk & 63) ^ ((p & 7) << 3));
  const float v = (sk < 1024) ? Wih1[(size_t)j * NH + sk]
                              : Whh1[(size_t)j * NH + (sk - 1024)];
  Wp1[idx] = (f16)v;
}

__global__ void pack_misc(const float* __restrict__ a0, const float* __restrict__ b0,
                          const float* __restrict__ a1, const float* __restrict__ b1,
                          float* __restrict__ bias0, float* __restrict__ bias1,
                          unsigned int* __restrict__ cnt) {
  const int j = blockIdx.x * 256 + threadIdx.x;
  if (j < 4096) { bias0[j] = a0[j] + b0[j]; bias1[j] = a1[j] + b1[j]; }
  if (j < 16) cnt[j] = 0;   // aCnt[8], bCnt[8] reset every call
}

// h state stored fp16 pre-swizzled (chunk swizzle keyed by row&7).
__global__ void init_h(const float* __restrict__ h_in,
                       f16* __restrict__ h0, f16* __restrict__ h1) {
  const int idx = blockIdx.x * 256 + threadIdx.x;  // exactly 2*1024*1024
  const int l = idx >> 20;
  const int rc = idx & 1048575;
  const int row = rc >> 10;
  const int dk = idx & 1023;
  const int sk = (dk & ~63) | ((dk & 63) ^ ((row & 7) << 3));
  const float hv = h_in[((size_t)l << 20) + ((size_t)row << 10) + sk];
  if (l == 0) h0[rc] = (f16)hv;
  else        h1[rc] = (f16)hv;
}

// Sum y partials for the last timestep (t = 335).
__global__ void final_y(const float* __restrict__ ypartT, const float* __restrict__ bout,
                        float* __restrict__ dout) {
  const int idx = blockIdx.x * 256 + threadIdx.x;  // exactly 9216
  const int row = idx & 1023;
  const int q = idx >> 10;
  float s = bout[q];
#pragma unroll
  for (int nb2 = 0; nb2 < 32; ++nb2) s += ypartT[(((q << 5) + nb2) << 10) + row];
  dout[(size_t)row * OUTSTRIDE + 335 * NQ + q] = s;
}

// ---------------------------------------------------------------------------
// Persistent kernel, 512 threads (8 waves = 2/SIMD), 4-slot LDS ring,
// stage-ahead 3, per-wave counted vmcnt ledger.
// Per iter: s_barrier (slot sc+3 free) -> issue stage(sc+3) (4 gll/wave)
//   -> s_waitcnt vmcnt(N) lgkmcnt(0) -> compute(sc).
// N = gll of stages sc+1..sc+3 per wave: normal 4+4+4=12; A-phase x-window
// (stage issued at g13 has 2 gll/wave) -> g13,g14,g15 = 10.
// Wave tiling 4Mx2N: wave owns 32 batch rows x 64 B-rows (=16 hcols x 4
// gates, n-frag == gate), acc[2][4], c-state [2][4] per layer in registers.
// h coherence: SC1 staging loads + sc0sc1 write-through stores + counter
// release (vmcnt(0) before cnt bump) — r5 scheme, no fences (r6 regressed).
// ---------------------------------------------------------------------------
__global__ __launch_bounds__(512, 1) void persist(
    const f16* __restrict__ Wp0, const f16* __restrict__ Wp1,
    const float* __restrict__ bias0, const float* __restrict__ bias1,
    f16* __restrict__ h0b0, f16* __restrict__ h0b1,
    f16* __restrict__ h1b0, f16* __restrict__ h1b1,
    unsigned int* __restrict__ cnt,
    const float* __restrict__ ff, const float* __restrict__ inpy,
    float* __restrict__ ypartT, const float* __restrict__ Wout,
    const float* __restrict__ bout, const float* __restrict__ c_in,
    float* __restrict__ dout) {
  __shared__ __align__(16) unsigned char lds8[131072];   // 4 x 32KB ring

  const int tid = threadIdx.x;
  const int wv = tid >> 6;          // 0..7
  const int ln = tid & 63;
  const int wr = wv >> 1;           // 0..3 (M)
  const int wc = wv & 1;            // 0..1 (N)
  const int blk = blockIdx.x;
  const int rb = (blk >> 3) & 7;
  const int cb = (blk & 7) * 4 + (blk >> 6);   // XCD-striped colblocks
  const int row0 = rb * 128;
  const int hcol0 = cb * 32;
  unsigned int* aCnt = cnt + rb;
  unsigned int* bCnt = cnt + 8 + rb;

  f16* h0arr[2] = {h0b0, h0b1};
  f16* h1arr[2] = {h1b0, h1b1};

  const int lanerow = ln & 15;
  const int xm = (ln & 7) << 4;
  const int kgrp = (ln >> 4) << 4;
  const int hcol = hcol0 + wc * 16 + lanerow;

  // c state lives in registers for the whole run
  float c0r[2][4], c1r[2][4];
#pragma unroll
  for (int m = 0; m < 2; ++m)
#pragma unroll
    for (int r = 0; r < 4; ++r) {
      const int row = row0 + wr * 32 + m * 16 + ((ln >> 4) << 2) + r;
      c0r[m][r] = c_in[(size_t)row * NH + hcol];
      c1r[m][r] = c_in[(size_t)(NBATCH * NH) + (size_t)row * NH + hcol];
    }

  const float b0i = bias0[hcol], b0f = bias0[NH + hcol],
              b0g = bias0[2 * NH + hcol], b0o = bias0[3 * NH + hcol];
  const float b1i = bias1[hcol], b1f = bias1[NH + hcol],
              b1g = bias1[2 * NH + hcol], b1o = bias1[3 * NH + hcol];

  auto stW = [&](const f16* W, int KDIM, int kt, int slot) {
#pragma unroll
    for (int i = 0; i < 2; ++i) {
      const int ci = wv * 2 + i;                 // 0..15
      const int tr = ci * 8 + (ln >> 3);
      gll_w(W + (size_t)(cb * 128 + tr) * KDIM + kt * 64 + (ln & 7) * 8,
            lds8 + slot * 32768 + 16384 + ci * 1024);
    }
  };
  auto stH = [&](const f16* h, int kb, int slot) {
#pragma unroll
    for (int i = 0; i < 2; ++i) {
      const int ci = wv * 2 + i;
      const int r = ci * 8 + (ln >> 3);
      gll_c(h + (((size_t)(row0 + r)) << 10) + kb + (ln & 7) * 8,
            lds8 + slot * 32768 + ci * 1024);
    }
  };

  f32x4 acc[2][4];
  const f32x4 zf = {0.0f, 0.0f, 0.0f, 0.0f};
#pragma unroll
  for (int m = 0; m < 2; ++m)
#pragma unroll
    for (int n = 0; n < 4; ++n) acc[m][n] = zf;

  auto compute = [&](int slot) {
    const unsigned char* Ab = lds8 + slot * 32768;
    const unsigned char* Bb = Ab + 16384;
#pragma unroll
    for (int ks = 0; ks < 2; ++ks) {
      const int kb = (kgrp + ks * 64) ^ xm;
      f16x8 afr[2], bfr[4];
#pragma unroll
      for (int m = 0; m < 2; ++m)
        afr[m] = *(const f16x8*)(Ab + (wr * 32 + m * 16 + lanerow) * 128 + kb);
#pragma unroll
      for (int n = 0; n < 4; ++n)
        bfr[n] = *(const f16x8*)(Bb + (wc * 64 + n * 16 + lanerow) * 128 + kb);
      __builtin_amdgcn_s_setprio(1);
#pragma unroll
      for (int m = 0; m < 2; ++m)
#pragma unroll
        for (int n = 0; n < 4; ++n)
          acc[m][n] = __builtin_amdgcn_mfma_f32_16x16x32_f16(afr[m], bfr[n], acc[m][n], 0, 0, 0);
      __builtin_amdgcn_s_setprio(0);
    }
  };

  // epilogue helper: hbuf (in freed slot) f32 [128][36] -> fp16 swizzled 16B
  // coherent stores (1 unit/thread = 8 cols of one row)
  auto h_widestore = [&](f16* hdst, float* hb) {
    const int r = tid >> 2;                 // block-local row 0..127
    const int u = tid & 3;                  // 8-col group
    const f32x4 lo = *(const f32x4*)(hb + r * 36 + u * 8);
    const f32x4 hi = *(const f32x4*)(hb + r * 36 + u * 8 + 4);
    f16x8 v;
#pragma unroll
    for (int j = 0; j < 4; ++j) { v[j] = (f16)lo[j]; v[4 + j] = (f16)hi[j]; }
    const int rowg = row0 + r;
    const int pb = ((hcol0 & 63) << 1) + u * 16;   // plain byte in 128B chunk
    void* p = (unsigned char*)hdst + (size_t)rowg * 2048 + ((hcol0 >> 6) << 7) +
              (pb ^ ((rowg & 7) << 4));
    store16_coherent(p, v);
  };

  // ---- prologue: stage A_0 tiles 0,1,2 into slots 0,1,2 (4 gll/wave each) --
  stH(h0arr[0], 0, 0);   stW(Wp0, K0, 1, 0);
  stH(h0arr[0], 64, 1);  stW(Wp0, K0, 2, 1);
  stH(h0arr[0], 128, 2); stW(Wp0, K0, 3, 2);

  int sc = 0;  // global slot counter (slot = sc & 3)

  for (int t = 0; t < NT; ++t) {
    const int p = t & 1;
    const f16* h0prev = h0arr[p];
    f16* h0new = h0arr[1 - p];
    const f16* h1prev = h1arr[p];
    f16* h1new = h1arr[1 - p];

    // ========== PHASE A (layer 0): 17 tiles, order kt = 1..16 then 0(x) =====
#pragma unroll 1
    for (int g = 0; g < 17; ++g) {
      __builtin_amdgcn_sched_barrier(0);
      __builtin_amdgcn_s_barrier();       // slot sc+3 free: its readers done
      __builtin_amdgcn_sched_barrier(0);
      const int cslot = sc & 3;
      const int tslot = (sc + 3) & 3;

      if (g == 13) {
        // gate on siblings' B_{t-1}: ypart ready (x feedback + y[t-1] out)
        if (t > 0) {
          if (tid == 0) spinGE(bCnt, 32u * (unsigned)t);
          __builtin_amdgcn_s_barrier();
          __builtin_amdgcn_sched_barrier(0);
        }
        unsigned char* xb = lds8 + tslot * 32768;
        if (tid < 128) {
          const int row = row0 + tid;
          float y0;
          if (t == 0) {
            y0 = inpy[row];
          } else {
            y0 = bout[0];
#pragma unroll
            for (int nb2 = 0; nb2 < 32; ++nb2)
              y0 += __hip_atomic_load(ypartT + (nb2 << 10) + row,
                                      __ATOMIC_RELAXED, __HIP_MEMORY_SCOPE_AGENT);
          }
          const float* fsrc = ff + ((size_t)row * NT + t) * NDFF;
          f16x8 xv;
          xv[0] = (f16)y0;
#pragma unroll
          for (int jj = 0; jj < 7; ++jj) xv[1 + jj] = (f16)fsrc[jj];
          *(f16x8*)(xb + tid * 128 + ((tid & 7) << 4)) = xv;
        }
        f16x8 zv;
#pragma unroll
        for (int jj = 0; jj < 8; ++jj) zv[jj] = (f16)0.0f;
        for (int idx = tid; idx < 128 * 7; idx += 512) {
          const int r = idx / 7;
          const int ch = 1 + (idx - r * 7);
          *(f16x8*)(xb + r * 128 + ((ch ^ (r & 7)) << 4)) = zv;
        }
        if (t > 0 && cb < NQ && tid < 128) {   // emit y[t-1]
          const int row = row0 + tid;
          float s = bout[cb];
#pragma unroll
          for (int nb2 = 0; nb2 < 32; ++nb2)
            s += __hip_atomic_load(ypartT + (((cb << 5) + nb2) << 10) + row,
                                   __ATOMIC_RELAXED, __HIP_MEMORY_SCOPE_AGENT);
          dout[(size_t)row * OUTSTRIDE + (t - 1) * NQ + cb] = s;
        }
        stW(Wp0, K0, 0, tslot);   // 2 gll/wave only
      } else {
        const int idx = g + 3;
        if (idx <= 15)      { stH(h0prev, idx * 64, tslot); stW(Wp0, K0, idx + 1, tslot); }
        else if (idx == 17) { stH(h1prev, 0, tslot);        stW(Wp1, K1, 16, tslot); }
        else if (idx == 18) { stH(h1prev, 64, tslot);       stW(Wp1, K1, 17, tslot); }
        else                { stH(h1prev, 128, tslot);      stW(Wp1, K1, 18, tslot); }
      }
      // counted wait: stage(sc) landed; stages sc+1..sc+3 stay in flight
      if (g >= 13 && g <= 15) asm volatile("s_waitcnt vmcnt(10) lgkmcnt(0)" ::: "memory");
      else                    asm volatile("s_waitcnt vmcnt(12) lgkmcnt(0)" ::: "memory");
      __builtin_amdgcn_sched_barrier(0);
      compute(cslot);
      ++sc;
    }

    // ---- A epilogue: layer-0 cell update -> hbuf -> wide coherent stores ----
    {
      // barrier: other waves may still be ds_reading the freed slot (x-slot)
      __builtin_amdgcn_s_barrier();
      float* hb = (float*)(lds8 + ((sc - 1) & 3) * 32768);
#pragma unroll
      for (int m = 0; m < 2; ++m) {
        const f32x4 vi = acc[m][0], vf = acc[m][1], vg = acc[m][2], vo = acc[m][3];
#pragma unroll
        for (int r = 0; r < 4; ++r) {
          const int rloc = wr * 32 + m * 16 + ((ln >> 4) << 2) + r;
          const float ig = sigf(vi[r] + b0i);
          const float fg = sigf(vf[r] + b0f);
          const float gg = tanhfast(vg[r] + b0g);
          const float og = sigf(vo[r] + b0o);
          const float cn = fg * c0r[m][r] + ig * gg;
          c0r[m][r] = cn;
          hb[rloc * 36 + wc * 16 + lanerow] = og * tanhfast(cn);
        }
        acc[m][0] = zf; acc[m][1] = zf; acc[m][2] = zf; acc[m][3] = zf;
      }
      asm volatile("s_waitcnt lgkmcnt(0)" ::: "memory");
      __builtin_amdgcn_s_barrier();
      h_widestore(h0new, hb);
      asm volatile("s_waitcnt vmcnt(0)" ::: "memory");  // h0 stores visible
      __builtin_amdgcn_s_barrier();
      if (tid == 0)
        __hip_atomic_fetch_add(aCnt, 1u, __ATOMIC_RELAXED, __HIP_MEMORY_SCOPE_AGENT);
    }

    // ========== PHASE B (layer 1): 32 tiles, order = h1prev k0..15, h0new k0..15
#pragma unroll 1
    for (int b = 0; b < 32; ++b) {
      __builtin_amdgcn_sched_barrier(0);
      __builtin_amdgcn_s_barrier();
      __builtin_amdgcn_sched_barrier(0);
      const int cslot = sc & 3;
      const int tslot = (sc + 3) & 3;

      if (b == 13) {  // gate h0new staging on all group-mates' phase A
        if (tid == 0) spinGE(aCnt, 32u * (unsigned)(t + 1));
        __builtin_amdgcn_s_barrier();
        __builtin_amdgcn_sched_barrier(0);
      }
      const int idx = b + 3;
      if (idx <= 15)      { stH(h1prev, idx * 64, tslot);        stW(Wp1, K1, 16 + idx, tslot); }
      else if (idx <= 31) { stH(h0new, (idx - 16) * 64, tslot);  stW(Wp1, K1, idx - 16, tslot); }
      else                { stH(h0new, (idx - 32) * 64, tslot);  stW(Wp0, K0, idx - 31, tslot); }
      asm volatile("s_waitcnt vmcnt(12) lgkmcnt(0)" ::: "memory");
      __builtin_amdgcn_sched_barrier(0);
      compute(cslot);
      ++sc;
    }

    // ---- B epilogue: layer-1 cell update; h1 wide stores + ypart ----
    {
      __builtin_amdgcn_s_barrier();   // freed slot may still be under ds_read
      float* hb = (float*)(lds8 + ((sc - 1) & 3) * 32768);
#pragma unroll
      for (int m = 0; m < 2; ++m) {
        const f32x4 vi = acc[m][0], vf = acc[m][1], vg = acc[m][2], vo = acc[m][3];
#pragma unroll
        for (int r = 0; r < 4; ++r) {
          const int rloc = wr * 32 + m * 16 + ((ln >> 4) << 2) + r;
          const float ig = sigf(vi[r] + b1i);
          const float fg = sigf(vf[r] + b1f);
          const float gg = tanhfast(vg[r] + b1g);
          const float og = sigf(vo[r] + b1o);
          const float cn = fg * c1r[m][r] + ig * gg;
          c1r[m][r] = cn;
          hb[rloc * 36 + wc * 16 + lanerow] = og * tanhfast(cn);
        }
        acc[m][0] = zf; acc[m][1] = zf; acc[m][2] = zf; acc[m][3] = zf;
      }
      asm volatile("s_waitcnt lgkmcnt(0)" ::: "memory");
      __builtin_amdgcn_s_barrier();
      h_widestore(h1new, hb);
      // y partials over this block's 32 h-cols: ypartT[q][cb][row]
      for (int task = tid; task < 128 * NQ; task += 512) {
        const int rloc = task & 127;
        const int q = task >> 7;
        const float* wq = Wout + q * NH + hcol0;
        float s = 0.0f;
#pragma unroll
        for (int c2 = 0; c2 < 32; ++c2) s += hb[rloc * 36 + c2] * wq[c2];
        __hip_atomic_store(ypartT + (size_t)((q << 5) + cb) * 1024 + row0 + rloc, s,
                           __ATOMIC_RELAXED, __HIP_MEMORY_SCOPE_AGENT);
      }
      asm volatile("s_waitcnt vmcnt(0)" ::: "memory");  // h1 + ypart visible
      __builtin_amdgcn_s_barrier();
      if (tid == 0)
        __hip_atomic_fetch_add(bCnt, 1u, __ATOMIC_RELAXED, __HIP_MEMORY_SCOPE_AGENT);
    }
  }
}

// ---------------------------------------------------------------------------
extern "C" void kernel_launch(void* const* d_in, const int* in_sizes, int n_in,
                              void* d_out, int out_size, void* d_ws, size_t ws_size,
                              hipStream_t stream) {
  const float* inpy = (const float*)d_in[2];
  const float* h_in = (const float*)d_in[3];
  const float* c_in = (const float*)d_in[4];
  const float* ff   = (const float*)d_in[5];
  const float* Wih0 = (const float*)d_in[9];
  const float* Whh0 = (const float*)d_in[10];
  const float* bih0 = (const float*)d_in[11];
  const float* bhh0 = (const float*)d_in[12];
  const float* Wih1 = (const float*)d_in[13];
  const float* Whh1 = (const float*)d_in[14];
  const float* bih1 = (const float*)d_in[15];
  const float* bhh1 = (const float*)d_in[16];
  const float* Wout = (const float*)d_in[17];
  const float* bout = (const float*)d_in[18];
  float* dout = (float*)d_out;

  unsigned char* ws = (unsigned char*)d_ws;
  size_t off = 0;
  auto alloc = [&](size_t bytes) -> void* {
    void* p = ws + off;
    off += (bytes + 255) & ~(size_t)255;
    return p;
  };
  f16* Wp0 = (f16*)alloc((size_t)4096 * K0 * 2);
  f16* Wp1 = (f16*)alloc((size_t)4096 * K1 * 2);
  f16* h0b0 = (f16*)alloc((size_t)NBATCH * NH * 2);
  f16* h0b1 = (f16*)alloc((size_t)NBATCH * NH * 2);
  f16* h1b0 = (f16*)alloc((size_t)NBATCH * NH * 2);
  f16* h1b1 = (f16*)alloc((size_t)NBATCH * NH * 2);
  float* bias0 = (float*)alloc(4096 * 4);
  float* bias1 = (float*)alloc(4096 * 4);
  float* ypartT = (float*)alloc((size_t)NQ * 32 * 1024 * 4);
  unsigned int* cnt = (unsigned int*)alloc(64);

  pack_w0<<<(4096 * K0) / 256, 256, 0, stream>>>(Wih0, Whh0, Wp0);
  pack_w1<<<(4096 * K1) / 256, 256, 0, stream>>>(Wih1, Whh1, Wp1);
  pack_misc<<<16, 256, 0, stream>>>(bih0, bhh0, bih1, bhh1, bias0, bias1, cnt);
  init_h<<<(2 * NBATCH * NH) / 256, 256, 0, stream>>>(h_in, h0b0, h1b0);

  persist<<<256, 512, 0, stream>>>(Wp0, Wp1, bias0, bias1, h0b0, h0b1, h1b0, h1b1,
                                   cnt, ff, inpy, ypartT, Wout, bout, c_in, dout);

  final_y<<<36, 256, 0, stream>>>(ypartT, bout, dout);
}

// Round 9
// 16394.078 us; speedup vs baseline: 1.3023x; 1.0505x over previous
//
#include <hip/hip_runtime.h>

typedef _Float16 f16;
typedef __attribute__((ext_vector_type(8))) _Float16 f16x8;
typedef __attribute__((ext_vector_type(4))) float f32x4;

#define NBATCH 1024
#define NH 1024
#define NT 336
#define NDFF 7
#define NQ 9
#define K0 1088   /* 64 (x padded) + 1024 (h0) */
#define K1 2048   /* 1024 (h0_new) + 1024 (h1) */
#define OUTSTRIDE (NT * NQ)
#define XAOFF 131072   /* dedicated 16KB x-tile A region (layer 0) */

__device__ __forceinline__ float sigf(float x) { return 1.0f / (1.0f + __expf(-x)); }
__device__ __forceinline__ float tanhfast(float x) { return 1.0f - 2.0f / (__expf(2.0f * x) + 1.0f); }

// plain cached global->LDS staging (16B/lane; LDS dst = uniform base + lane*16)
__device__ __forceinline__ void gll(const void* g, void* l) {
  __builtin_amdgcn_global_load_lds((const __attribute__((address_space(1))) void*)g,
                                   (__attribute__((address_space(3))) void*)l, 16, 0, 0);
}

// ---------------------------------------------------------------------------
// Weight pack: rows permuted so LDS B-tile row p: gate=(p>>4)&3,
// hcol_local=(p>>6)*16+(p&15) -> MFMA n-index == gate.
// k pre-swizzled per 64-col chunk: dst_k = (k&~63)|((k&63)^((p&7)<<3)).
// ---------------------------------------------------------------------------
__global__ void pack_w0(const float* __restrict__ Wih0, const float* __restrict__ Whh0,
                        f16* __restrict__ Wp0) {
  const int idx = blockIdx.x * 256 + threadIdx.x;  // exactly 4096*K0
  const int pr = idx / K0;
  const int dk = idx - pr * K0;
  const int cb = pr >> 7, p = pr & 127;
  const int gate = (p >> 4) & 3;
  const int hl = ((p >> 6) << 4) | (p & 15);
  const int j = (gate << 10) + (cb << 5) + hl;
  const int sk = (dk & ~63) | ((dk & 63) ^ ((p & 7) << 3));
  float v;
  if (sk < 8) v = Wih0[j * 8 + sk];
  else if (sk < 64) v = 0.0f;
  else v = Whh0[(size_t)j * NH + (sk - 64)];
  Wp0[idx] = (f16)v;
}

__global__ void pack_w1(const float* __restrict__ Wih1, const float* __restrict__ Whh1,
                        f16* __restrict__ Wp1) {
  const int idx = blockIdx.x * 256 + threadIdx.x;  // exactly 4096*2048
  const int pr = idx >> 11;
  const int dk = idx & 2047;
  const int cb = pr >> 7, p = pr & 127;
  const int gate = (p >> 4) & 3;
  const int hl = ((p >> 6) << 4) | (p & 15);
  const int j = (gate << 10) + (cb << 5) + hl;
  const int sk = (dk & ~63) | ((dk & 63) ^ ((p & 7) << 3));
  const float v = (sk < 1024) ? Wih1[(size_t)j * NH + sk]
                              : Whh1[(size_t)j * NH + (sk - 1024)];
  Wp1[idx] = (f16)v;
}

__global__ void pack_bias(const float* __restrict__ a0, const float* __restrict__ b0,
                          const float* __restrict__ a1, const float* __restrict__ b1,
                          float* __restrict__ bias0, float* __restrict__ bias1) {
  const int j = blockIdx.x * 256 + threadIdx.x;
  if (j < 4096) { bias0[j] = a0[j] + b0[j]; bias1[j] = a1[j] + b1[j]; }
}

// h fp16 pre-swizzled (chunk swizzle keyed by row&7)
__global__ void init_h(const float* __restrict__ h_in,
                       f16* __restrict__ h0, f16* __restrict__ h1) {
  const int idx = blockIdx.x * 256 + threadIdx.x;  // exactly 2*1024*1024
  const int l = idx >> 20;
  const int rc = idx & 1048575;
  const int row = rc >> 10;
  const int dk = idx & 1023;
  const int sk = (dk & ~63) | ((dk & 63) ^ ((row & 7) << 3));
  const float hv = h_in[((size_t)l << 20) + ((size_t)row << 10) + sk];
  if (l == 0) h0[rc] = (f16)hv;
  else        h1[rc] = (f16)hv;
}

// c packed so each thread's 16 values are lane-coalesced:
// cpk[l][ ((rb*32+cb)*4+wv)*1024 + j*64 + ln ], j = m*4+r
__global__ void init_c(const float* __restrict__ c_in, float* __restrict__ c0p,
                       float* __restrict__ c1p) {
  const int idx = blockIdx.x * 256 + threadIdx.x;  // exactly 2*1024*1024
  const int l = idx >> 20;
  const int rem = idx & 1048575;
  const int ln = rem & 63;
  const int j = (rem >> 6) & 15;
  const int wv = (rem >> 10) & 3;
  const int cb = (rem >> 12) & 31;
  const int rb = rem >> 17;
  const int row = rb * 128 + (wv >> 1) * 64 + (j >> 2) * 16 + ((ln >> 4) & 3) * 4 + (j & 3);
  const int col = cb * 32 + (wv & 1) * 16 + (ln & 15);
  const float v = c_in[((size_t)l << 20) + ((size_t)row << 10) + col];
  if (l == 0) c0p[rem] = v; else c1p[rem] = v;
}

__global__ void final_y(const float* __restrict__ ypartT, const float* __restrict__ bout,
                        float* __restrict__ dout) {
  const int idx = blockIdx.x * 256 + threadIdx.x;  // exactly 9216
  const int row = idx & 1023;
  const int q = idx >> 10;
  float s = bout[q];
#pragma unroll
  for (int nb2 = 0; nb2 < 32; ++nb2) s += ypartT[(((q << 5) + nb2) << 10) + row];
  dout[(size_t)row * OUTSTRIDE + 335 * NQ + q] = s;
}

// ---------------------------------------------------------------------------
// Step kernel, BK=128, STAGE-AHEAD-1 (race fix for round 8's stage-ahead-2
// on a 2-slot ring, which overwrote the slot being computed).
// Tile 128(M)x128(N gates), 4 waves 2x2 (64x64 each).
// LDS: 2 slots x 64KB (A 32KB @+0, B 32KB @+32768) + 16KB xA region (L0).
// Schedule per iter i:
//   stage t_{i+1} -> slot (i+1)&1   (slot free: t_{i-1} readers done at the
//                                    END-barrier of iter i-1)
//   compute t_i   <- slot  i&1      (t_i landed: every wave drained vmcnt(0)
//                                    BEFORE iter i-1's end barrier)
//   s_waitcnt vmcnt(0)              (t_{i+1}: only outstanding vmem; it
//                                    overlapped the whole compute)
//   s_barrier                       (publishes t_{i+1} + frees slot i&1)
// This is the r2-proven wait-BEFORE-barrier publication pattern.
// Coherence: all plain loads/stores — kernel boundaries order everything.
// ---------------------------------------------------------------------------
template <int L>
__global__ __launch_bounds__(256, 1) void step_kernel(
    const f16* __restrict__ Wp, const float* __restrict__ bias,
    const f16* __restrict__ hA0, const f16* __restrict__ hA1,
    f16* __restrict__ hout, float* __restrict__ cpk,
    const float* __restrict__ ff, const float* __restrict__ inpy,
    float* __restrict__ ypartT, const float* __restrict__ Wout,
    const float* __restrict__ bout, float* __restrict__ dout, int t) {
  constexpr int KDIM = L ? K1 : K0;
  constexpr int NTILE = L ? 16 : 9;
  __shared__ __align__(16) unsigned char lds8[147456];  // 2x64KB + 16KB xA

  const int tid = threadIdx.x;
  const int wv = tid >> 6;
  const int ln = tid & 63;
  const int wr = wv >> 1, wc = wv & 1;
  const int blk = blockIdx.x;
  const int rb = (blk >> 3) & 7;
  const int cb = (blk & 7) * 4 + (blk >> 6);   // XCD-striped colblocks
  const int row0 = rb * 128;
  const int hcol0 = cb * 32;

  const int lanerow = ln & 15;
  const int xm = (ln & 7) << 4;
  const int kgrp = (ln >> 4) << 4;
  const int hcol = hcol0 + wc * 16 + lanerow;

  // stage a full 128k tile (A 8 gll + B 8 gll per wave); 256B LDS rows
  auto stage128 = [&](int j, int slot) {
    const f16* hsrc; int koff, wk0;
    if (L) {
      if (j < 8) { hsrc = hA0; koff = j * 128; } else { hsrc = hA1; koff = (j - 8) * 128; }
      wk0 = j * 128;
    } else {
      hsrc = hA0; koff = (j - 1) * 128; wk0 = 64 + (j - 1) * 128;
    }
    unsigned char* sb = lds8 + slot * 65536;
#pragma unroll
    for (int ii = 0; ii < 8; ++ii) {
      const int ci = wv * 8 + ii;
      const int r = ci * 4 + (ln >> 4);                 // 4 rows/gll, 256B rows
      gll(hsrc + (((size_t)(row0 + r)) << 10) + koff + (ln & 15) * 8, sb + ci * 1024);
    }
#pragma unroll
    for (int ii = 0; ii < 8; ++ii) {
      const int ci = wv * 8 + ii;
      const int pr = ci * 4 + (ln >> 4);
      gll(Wp + (size_t)(cb * 128 + pr) * KDIM + wk0 + (ln & 15) * 8,
          sb + 32768 + ci * 1024);
    }
  };

  f32x4 acc[4][4];
  const f32x4 zf = {0.0f, 0.0f, 0.0f, 0.0f};
#pragma unroll
  for (int m = 0; m < 4; ++m)
#pragma unroll
    for (int n = 0; n < 4; ++n) acc[m][n] = zf;

  auto compute128 = [&](int slot) {
    const unsigned char* Ab = lds8 + slot * 65536;
    const unsigned char* Bb = Ab + 32768;
#pragma unroll
    for (int ks = 0; ks < 4; ++ks) {
      const int kb = ((ks >> 1) << 7) + ((kgrp + ((ks & 1) << 6)) ^ xm);
      f16x8 afr[4], bfr[4];
#pragma unroll
      for (int m = 0; m < 4; ++m)
        afr[m] = *(const f16x8*)(Ab + (wr * 64 + m * 16 + lanerow) * 256 + kb);
#pragma unroll
      for (int n = 0; n < 4; ++n)
        bfr[n] = *(const f16x8*)(Bb + (wc * 64 + n * 16 + lanerow) * 256 + kb);
      __builtin_amdgcn_s_setprio(1);
#pragma unroll
      for (int m = 0; m < 4; ++m)
#pragma unroll
        for (int n = 0; n < 4; ++n)
          acc[m][n] = __builtin_amdgcn_mfma_f32_16x16x32_f16(afr[m], bfr[n], acc[m][n], 0, 0, 0);
      __builtin_amdgcn_s_setprio(0);
    }
  };

  // ---- prologue: build/stage t0, drain, publish ----
  if (!L) {
    if (tid < 128) {
      const int row = row0 + tid;
      float y0;
      if (t == 0) {
        y0 = inpy[row];
      } else {
        y0 = bout[0];
        const float* yp = ypartT + row;
#pragma unroll
        for (int nb2 = 0; nb2 < 32; ++nb2) y0 += yp[nb2 << 10];
      }
      const float* fsrc = ff + ((size_t)row * NT + t) * NDFF;
      f16x8 xv;
      xv[0] = (f16)y0;
#pragma unroll
      for (int jj = 0; jj < 7; ++jj) xv[1 + jj] = (f16)fsrc[jj];
      *(f16x8*)(lds8 + XAOFF + tid * 128 + ((tid & 7) << 4)) = xv;
    }
    f16x8 zv;
#pragma unroll
    for (int jj = 0; jj < 8; ++jj) zv[jj] = (f16)0.0f;
    for (int idx = tid; idx < 128 * 7; idx += 256) {
      const int r = idx / 7;
      const int ch = 1 + (idx - r * 7);
      *(f16x8*)(lds8 + XAOFF + r * 128 + ((ch ^ (r & 7)) << 4)) = zv;
    }
    if (t > 0 && cb < NQ && tid < 128) {   // emit y[t-1]
      const int row = row0 + tid;
      float s = bout[cb];
      const float* yp = ypartT + ((size_t)(cb << 5) << 10) + row;
#pragma unroll
      for (int nb2 = 0; nb2 < 32; ++nb2) s += yp[nb2 << 10];
      dout[(size_t)row * OUTSTRIDE + (t - 1) * NQ + cb] = s;
    }
    // stage t0 B (64k: 4 gll/wave, 128B rows) into slot0 B-region
#pragma unroll
    for (int ii = 0; ii < 4; ++ii) {
      const int ci = wv * 4 + ii;
      gll(Wp + (size_t)(cb * 128 + ci * 8 + (ln >> 3)) * KDIM + (ln & 7) * 8,
          lds8 + 32768 + ci * 1024);
    }
  } else {
    stage128(0, 0);
  }
  asm volatile("s_waitcnt vmcnt(0) lgkmcnt(0)" ::: "memory");
  __builtin_amdgcn_s_barrier();      // t0 (+x) published to all waves

  // ---- main K loop: stage(i+1) -> compute(i) -> drain -> barrier ----
#pragma unroll 1
  for (int i = 0; i < NTILE; ++i) {
    __builtin_amdgcn_sched_barrier(0);
    if (i + 1 < NTILE) stage128(i + 1, (i + 1) & 1);
    __builtin_amdgcn_sched_barrier(0);
    if (!L && i == 0) {
      // 64k x-tile: A from xA region (128B rows), B from slot0 (128B rows)
      const unsigned char* Ab = lds8 + XAOFF;
      const unsigned char* Bb = lds8 + 32768;
#pragma unroll
      for (int ks = 0; ks < 2; ++ks) {
        const int kb = (kgrp + (ks << 6)) ^ xm;
        f16x8 afr[4], bfr[4];
#pragma unroll
        for (int m = 0; m < 4; ++m)
          afr[m] = *(const f16x8*)(Ab + (wr * 64 + m * 16 + lanerow) * 128 + kb);
#pragma unroll
        for (int n = 0; n < 4; ++n)
          bfr[n] = *(const f16x8*)(Bb + (wc * 64 + n * 16 + lanerow) * 128 + kb);
        __builtin_amdgcn_s_setprio(1);
#pragma unroll
        for (int m = 0; m < 4; ++m)
#pragma unroll
          for (int n = 0; n < 4; ++n)
            acc[m][n] = __builtin_amdgcn_mfma_f32_16x16x32_f16(afr[m], bfr[n], acc[m][n], 0, 0, 0);
        __builtin_amdgcn_s_setprio(0);
      }
    } else {
      compute128(i & 1);
    }
    __builtin_amdgcn_sched_barrier(0);
    // drain t_{i+1} (only outstanding vmem; overlapped the whole compute),
    // then publish: after this barrier every wave may read t_{i+1} and
    // overwrite slot i&1.
    asm volatile("s_waitcnt vmcnt(0)" ::: "memory");
    __builtin_amdgcn_s_barrier();
    __builtin_amdgcn_sched_barrier(0);
  }

  // ---- epilogue: cell update (register-local; n-frag == gate) ----
  // hbuf in the slot OPPOSITE the last tile; untouched since its last
  // publication barrier -> safe immediately (all waves past final barrier).
  float* hb = (float*)(lds8 + (L ? 0 : 65536));
  const float bi = bias[hcol];
  const float bf = bias[NH + hcol];
  const float bg = bias[2 * NH + hcol];
  const float bo = bias[3 * NH + hcol];
  const int cbase = ((rb * 32 + cb) * 4 + wv) * 1024;
#pragma unroll
  for (int m = 0; m < 4; ++m) {
    const f32x4 vi = acc[m][0], vf = acc[m][1], vg = acc[m][2], vo = acc[m][3];
#pragma unroll
    for (int r = 0; r < 4; ++r) {
      const int j = m * 4 + r;
      const int rloc = wr * 64 + m * 16 + ((ln >> 4) << 2) + r;
      const float c_old = cpk[cbase + j * 64 + ln];
      const float ig = sigf(vi[r] + bi);
      const float fg = sigf(vf[r] + bf);
      const float gg = tanhfast(vg[r] + bg);
      const float og = sigf(vo[r] + bo);
      const float cn = fg * c_old + ig * gg;
      cpk[cbase + j * 64 + ln] = cn;
      hb[rloc * 36 + wc * 16 + lanerow] = og * tanhfast(cn);
    }
  }
  asm volatile("s_waitcnt lgkmcnt(0)" ::: "memory");
  __builtin_amdgcn_s_barrier();
  // wide h store: 2 units/thread, each = 8 cols of one row, 16B coalesced
#pragma unroll
  for (int u2 = 0; u2 < 2; ++u2) {
    const int unit = tid * 2 + u2;          // 0..511
    const int r = unit >> 2;
    const int u = unit & 3;
    const f32x4 lo = *(const f32x4*)(hb + r * 36 + u * 8);
    const f32x4 hi = *(const f32x4*)(hb + r * 36 + u * 8 + 4);
    f16x8 v;
#pragma unroll
    for (int jj = 0; jj < 4; ++jj) { v[jj] = (f16)lo[jj]; v[4 + jj] = (f16)hi[jj]; }
    const int rowg = row0 + r;
    const int pb = ((hcol0 & 63) << 1) + u * 16;
    *(f16x8*)((unsigned char*)hout + (size_t)rowg * 2048 + ((hcol0 >> 6) << 7) +
              (pb ^ ((rowg & 7) << 4))) = v;
  }
  if (L) {
    // y partials over this block's 32 h-cols: ypartT[q][cb][row]
    for (int task = tid; task < 128 * NQ; task += 256) {
      const int rloc = task & 127;
      const int q = task >> 7;
      const float* wq = Wout + q * NH + hcol0;
      float s = 0.0f;
#pragma unroll
      for (int c2 = 0; c2 < 32; ++c2) s += hb[rloc * 36 + c2] * wq[c2];
      ypartT[(size_t)((q << 5) + cb) * 1024 + row0 + rloc] = s;
    }
  }
}

// ---------------------------------------------------------------------------
extern "C" void kernel_launch(void* const* d_in, const int* in_sizes, int n_in,
                              void* d_out, int out_size, void* d_ws, size_t ws_size,
                              hipStream_t stream) {
  const float* inpy = (const float*)d_in[2];
  const float* h_in = (const float*)d_in[3];
  const float* c_in = (const float*)d_in[4];
  const float* ff   = (const float*)d_in[5];
  const float* Wih0 = (const float*)d_in[9];
  const float* Whh0 = (const float*)d_in[10];
  const float* bih0 = (const float*)d_in[11];
  const float* bhh0 = (const float*)d_in[12];
  const float* Wih1 = (const float*)d_in[13];
  const float* Whh1 = (const float*)d_in[14];
  const float* bih1 = (const float*)d_in[15];
  const float* bhh1 = (const float*)d_in[16];
  const float* Wout = (const float*)d_in[17];
  const float* bout = (const float*)d_in[18];
  float* dout = (float*)d_out;

  unsigned char* ws = (unsigned char*)d_ws;
  size_t off = 0;
  auto alloc = [&](size_t bytes) -> void* {
    void* p = ws + off;
    off += (bytes + 255) & ~(size_t)255;
    return p;
  };
  f16* Wp0 = (f16*)alloc((size_t)4096 * K0 * 2);
  f16* Wp1 = (f16*)alloc((size_t)4096 * K1 * 2);
  f16* h0b0 = (f16*)alloc((size_t)NBATCH * NH * 2);
  f16* h0b1 = (f16*)alloc((size_t)NBATCH * NH * 2);
  f16* h1b0 = (f16*)alloc((size_t)NBATCH * NH * 2);
  f16* h1b1 = (f16*)alloc((size_t)NBATCH * NH * 2);
  float* bias0 = (float*)alloc(4096 * 4);
  float* bias1 = (float*)alloc(4096 * 4);
  float* ypartT = (float*)alloc((size_t)NQ * 32 * 1024 * 4);
  float* c0p = (float*)alloc((size_t)NBATCH * NH * 4);
  float* c1p = (float*)alloc((size_t)NBATCH * NH * 4);
  f16* h0b[2] = {h0b0, h0b1};
  f16* h1b[2] = {h1b0, h1b1};

  pack_w0<<<(4096 * K0) / 256, 256, 0, stream>>>(Wih0, Whh0, Wp0);
  pack_w1<<<(4096 * K1) / 256, 256, 0, stream>>>(Wih1, Whh1, Wp1);
  pack_bias<<<16, 256, 0, stream>>>(bih0, bhh0, bih1, bhh1, bias0, bias1);
  init_h<<<(2 * NBATCH * NH) / 256, 256, 0, stream>>>(h_in, h0b0, h1b0);
  init_c<<<(2 * NBATCH * NH) / 256, 256, 0, stream>>>(c_in, c0p, c1p);

  for (int t = 0; t < NT; ++t) {
    const int p = t & 1;
    // layer 0: A = [x | h0prev], writes h0new; also y[t-1] output + feedback
    step_kernel<0><<<256, 256, 0, stream>>>(Wp0, bias0, h0b[p], nullptr, h0b[1 - p],
                                            c0p, ff, inpy, ypartT, nullptr, bout, dout, t);
    // layer 1: A = [h0new | h1prev], writes h1new + y partials
    step_kernel<1><<<256, 256, 0, stream>>>(Wp1, bias1, h0b[1 - p], h1b[p], h1b[1 - p],
                                            c1p, nullptr, nullptr, ypartT, Wout, bout, dout, t);
  }
  final_y<<<36, 256, 0, stream>>>(ypartT, bout, dout);
}